// Round 14
// baseline (144.525 us; speedup 1.0000x reference)
//
#include <hip/hip_runtime.h>
#include <hip/hip_bf16.h>
#include <cstdint>

#define NB 16
#define CI 256
#define CO 256
#define HH 64
#define WW 64
#define CC 512
#define HP 66
#define WP 66

typedef short short8 __attribute__((ext_vector_type(8)));
typedef float floatx4 __attribute__((ext_vector_type(4)));
typedef unsigned int uintx4 __attribute__((ext_vector_type(4)));

__device__ __forceinline__ void g2lds16(const void* g, void* l) {
  __builtin_amdgcn_global_load_lds((const __attribute__((address_space(1))) void*)g,
                                   (__attribute__((address_space(3))) void*)l, 16, 0, 0);
}

#define ASM_VMCNT0() do { __builtin_amdgcn_sched_barrier(0);               \
                          asm volatile("s_waitcnt vmcnt(0)" ::: "memory"); \
                          __builtin_amdgcn_sched_barrier(0); } while (0)
#define RAW_BAR() do { __builtin_amdgcn_sched_barrier(0);  \
                       __builtin_amdgcn_s_barrier();       \
                       __builtin_amdgcn_sched_barrier(0); } while (0)

// ---------------- MLP layer (split version: 64-block grids, latency-friendly) ----------------
template<int KD, int N, bool SILU, bool PLUSONE, int BJ>
__global__ void k_mlp(const float* __restrict__ in, const float* __restrict__ w,
                      const float* __restrict__ bias, float* __restrict__ out) {
  __shared__ float4 sin4[KD / 4];
  const int nb = N / BJ;
  int b = blockIdx.x / nb;
  int j = (blockIdx.x % nb) * BJ + threadIdx.x;
  const float4* in4 = reinterpret_cast<const float4*>(in + (size_t)b * KD);
  for (int k = threadIdx.x; k < KD / 4; k += BJ) sin4[k] = in4[k];
  __syncthreads();
  float acc = bias[j];
  const float4* wr = reinterpret_cast<const float4*>(w + (size_t)j * KD);
#pragma unroll 8
  for (int kk = 0; kk < KD / 4; ++kk) {
    float4 wv = wr[kk];
    float4 sv = sin4[kk];
    acc += wv.x * sv.x + wv.y * sv.y + wv.z * sv.z + wv.w * sv.w;
  }
  if (SILU) acc = acc / (1.0f + __expf(-acc));
  if (PLUSONE) acc += 1.0f;
  out[(size_t)b * N + j] = acc;
}

// ---------------- weight repack fp32 [O][I][3][3] -> bf16 Wt2[t][kc][ks][o][8]; wsq ----------------
// Layout chosen so a conv wave's af fragment load is PERFECTLY COALESCED from global:
// element (t,o,i) -> Wt2[t*65536 + ((i>>5)*4 + ((i>>3)&3))*2048 + o*8 + (i&7)].
__global__ void k_repack(const float* __restrict__ cw, __hip_bfloat16* __restrict__ Wt2,
                         float* __restrict__ wsq) {
  int gid = blockIdx.x * 256 + threadIdx.x;   // gid = o*CI + i
  if (gid >= CO * CI) return;
  int o = gid >> 8;
  int i = gid & 255;
  int base_i = ((i >> 5) * 4 + ((i >> 3) & 3)) * 2048 + o * 8 + (i & 7);
  const float* p = cw + (size_t)gid * 9;
  float s = 0.0f;
#pragma unroll
  for (int t = 0; t < 9; ++t) {
    float v = p[t];
    s += v * v;
    Wt2[(size_t)t * 65536 + base_i] = __float2bfloat16(v);
  }
  wsq[gid] = s;
}

// ---------------- demod ----------------
__global__ void k_demod(const float* __restrict__ wsq, const float* __restrict__ scale,
                        float* __restrict__ demod) {
  __shared__ float s2[CI];
  int b = blockIdx.x;
  int o = threadIdx.x;
  float sv = scale[b * CI + o];
  s2[o] = sv * sv;
  __syncthreads();
  float acc = 0.0f;
  const float4* wr = reinterpret_cast<const float4*>(wsq + (size_t)o * CI);
  const float4* s4 = reinterpret_cast<const float4*>(s2);
#pragma unroll 8
  for (int i = 0; i < CI / 4; ++i) {
    float4 wv = wr[i];
    float4 sq = s4[i];
    acc += wv.x * sq.x + wv.y * sq.y + wv.z * sq.z + wv.w * sq.w;
  }
  demod[b * CO + o] = rsqrtf(acc + 1e-8f);
}

// ---------------- X (NCHW fp32) * scale -> Xs (padded NHWC bf16); halo zeroing fused ----------------
__global__ void k_scalex(const float* __restrict__ X, const float* __restrict__ scale,
                         __hip_bfloat16* __restrict__ Xs) {
  __shared__ float tile[64][68];
  __shared__ float ssc[64];
  int bid = blockIdx.x;                 // grid = NB * 64(h) * 4(ichunk)
  int b = bid >> 8;
  int rem = bid & 255;
  int h = rem >> 2;
  int i0 = (rem & 3) * 64;
  int t = threadIdx.x;
  if (t < 64) ssc[t] = scale[b * CI + i0 + t];

  __hip_bfloat16* xs_img = Xs + (size_t)b * HP * WP * CI;
  uintx4 z = {0u, 0u, 0u, 0u};
  if (t < 16) {
    int px = (t >> 3) * 65;
    int sl = t & 7;
    *reinterpret_cast<uintx4*>(xs_img + (((size_t)(h + 1)) * WP + px) * CI + i0 + sl * 8) = z;
  }
  if (h == 0) {
    for (int u = t; u < 66 * 8; u += 256) {
      int px = u >> 3, sl = u & 7;
      *reinterpret_cast<uintx4*>(xs_img + ((size_t)px) * CI + i0 + sl * 8) = z;
    }
  }
  if (h == 63) {
    for (int u = t; u < 66 * 8; u += 256) {
      int px = u >> 3, sl = u & 7;
      *reinterpret_cast<uintx4*>(xs_img + ((size_t)65 * WP + px) * CI + i0 + sl * 8) = z;
    }
  }

  const float* src = X + (((size_t)b * CI + i0) * HH + h) * WW;
  int ii_base = t >> 4;                 // 0..3
  int w4 = (t & 15) * 4;
#pragma unroll
  for (int r2 = 0; r2 < 4; ++r2) {
    int ii = r2 * 16 + ii_base;
    int key = ((ii >> 3) & 7) << 2;
    *reinterpret_cast<float4*>(&tile[ii][w4 ^ key]) =
        *reinterpret_cast<const float4*>(src + (size_t)ii * HH * WW + w4);
  }
  __syncthreads();
  int u = t & 7;
  int wl = t >> 3;
  int key = u << 2;
#pragma unroll
  for (int iter = 0; iter < 2; ++iter) {
    int w2 = wl + iter * 32;
    union { unsigned short us[8]; uintx4 v; } pk;
#pragma unroll
    for (int j = 0; j < 8; ++j) {
      int ii = u * 8 + j;
      float v = tile[ii][w2 ^ key] * ssc[ii];
      __hip_bfloat16 hb = __float2bfloat16(v);
      pk.us[j] = *reinterpret_cast<unsigned short*>(&hb);
    }
    *reinterpret_cast<uintx4*>(xs_img + (((size_t)(h + 1)) * WP + (w2 + 1)) * CI + i0 + u * 8) = pk.v;
  }
}

// ---------------- main conv: NO per-tap barriers — A direct from global (coalesced) ----------------
// BM=128 o x BN=256 px; 256 threads = 4 waves (2 o-groups x 2 px-groups); wave-tile 64o x 128px.
// A straight from Wt2 (k-major repack) via 4 coalesced global_load_dwordx4 per tap per wave —
// no A-LDS, hence NO per-tap barrier. bq: 8 ds_reads from the chunk-stable X buffer. Waves
// drift freely within a chunk: LDS reads / af L2 latency of one wave overlap other waves'
// MFMAs (per-tap barriers previously serialized read-phase + MFMA-phase block-wide:
// 2450 cyc/tap ~ 1152 LDS + 1241 MFMA in series).
// Sync invariants (2): (a) chunk barrier + per-wave vmcnt(0) -> X(c+1) staged before read;
// (b) staging targets xbuf[(c+1)&1] while reads hit xbuf[c&1]. af JIT in 16 regs (NOT
// double-buffered — the 128-arch-reg cap, rounds 7/9/10). LDS: 2 x 28672 -> 2 blocks/CU.
__global__ __launch_bounds__(256, 2)
void k_conv(const __hip_bfloat16* __restrict__ Xs, const __hip_bfloat16* __restrict__ Wt2,
            const float* __restrict__ demod, float* __restrict__ out) {
  __shared__ __align__(16) char lds[2 * 28672];
  char* sX0 = lds;

  // bijective XCD swizzle: 512 blocks -> 64 consecutive wg per XCD = 2 images per XCD L2
  int wg = (blockIdx.x & 7) * 64 + (blockIdx.x >> 3);
  int b = wg >> 5;
  int rem = wg & 31;
  int ht = rem >> 1;                    // 0..15
  int ob = rem & 1;
  int h0 = ht * 4;                      // 4 output rows
  int o0 = ob * 128;

  int tid = threadIdx.x;
  int wv = tid >> 6;                    // 0..3
  int lane = tid & 63;
  int lhi = lane >> 4;                  // 0..3
  int llo = lane & 15;                  // 0..15
  int wo2 = wv >> 1;                    // 0..1  o-group
  int wpx = wv & 1;                     // 0..1  px-group (2 rows)

  floatx4 acc[4][8];
#pragma unroll
  for (int m = 0; m < 4; ++m)
#pragma unroll
    for (int n = 0; n < 8; ++n) acc[m][n] = (floatx4){0.f, 0.f, 0.f, 0.f};

  const __hip_bfloat16* xs_img = Xs + (size_t)b * HP * WP * CI;

  // X staging slots: 28 1-KB blocks, 7 per wave; source carries the read-side k-slot XOR.
  int xoff[7];
#pragma unroll
  for (int s = 0; s < 7; ++s) {
    int j = wv + 4 * s;
    int pr = 16 * j + (lane >> 2);      // LDS pixel-row 0..447
    int prc = pr > 431 ? 431 : pr;      // pad block: clamp source (never read)
    int lr = prc / 72;
    int wp = prc - lr * 72;
    if (wp > 65) wp = 65;               // pitch pad: clamp source (never read)
    int ksl = (lane & 3) ^ ((pr >> 1) & 3);
    xoff[s] = ((h0 + lr) * WP + wp) * CI + ksl * 8;
  }
  // af global element-offsets within a (t,kc) segment of Wt2: lhi*2048 + o*8
  int aofs[4];
#pragma unroll
  for (int m = 0; m < 4; ++m)
    aofs[m] = lhi * 2048 + (o0 + wo2 * 64 + m * 16 + llo) * 8;

  // ---- prologue: stage X(0) fully; drain; barrier ----
#pragma unroll
  for (int s = 0; s < 7; ++s)
    g2lds16(xs_img + xoff[s], sX0 + (wv + 4 * s) * 1024);
  ASM_VMCNT0();
  RAW_BAR();

  for (int c = 0; c < 8; ++c) {
    const char* xbuf = sX0 + (c & 1) * 28672;
#pragma unroll
    for (int t = 0; t < 9; ++t) {
      // ---- af: 4 coalesced global loads from the k-major Wt2 (segment t*8+c) ----
      const __hip_bfloat16* wb = Wt2 + (size_t)(t * 8 + c) * 8192;
      short8 af[4];
#pragma unroll
      for (int m = 0; m < 4; ++m)
        af[m] = *reinterpret_cast<const short8*>(wb + aofs[m]);
      // ---- X(c+1) staging: 1 g2lds per wave at taps 0..6 ----
      if (t <= 6 && c < 7)
        g2lds16(xs_img + xoff[t] + (c + 1) * 32,
                sX0 + ((c + 1) & 1) * 28672 + (wv + 4 * t) * 1024);
      // ---- bq: 8 ds_reads from chunk-stable xbuf (no sync needed) ----
      int kh = t / 3;
      int kw = t - kh * 3;
      short8 bq[8];
#pragma unroll
      for (int n = 0; n < 8; ++n) {
        int stripe = wpx * 2 + (n >> 2) + kh;            // 0..5
        int px = (n & 3) * 16 + llo + kw;                // 0..65
        int prl = stripe * 72 + px;
        bq[n] = *reinterpret_cast<const short8*>(
            xbuf + prl * 64 + ((lhi ^ ((prl >> 1) & 3)) << 4));
      }
      // compiler inserts counted vmcnt for af (g2lds stays in flight) + lgkmcnt for bq.
      __builtin_amdgcn_s_setprio(1);
#pragma unroll
      for (int n = 0; n < 8; ++n)
#pragma unroll
        for (int m = 0; m < 4; ++m)
          acc[m][n] = __builtin_amdgcn_mfma_f32_16x16x32_bf16(af[m], bq[n], acc[m][n], 0, 0, 0);
      __builtin_amdgcn_s_setprio(0);
    }
    // ---- chunk boundary: drain own g2lds, then block-wide rendezvous ----
    ASM_VMCNT0();
    if (c < 7) RAW_BAR();
  }

  // ---- epilogue: demod multiply, fp32 NCHW stores ----
#pragma unroll
  for (int m = 0; m < 4; ++m) {
    int obase_o = o0 + wo2 * 64 + m * 16 + lhi * 4;
    float4 dmv = *reinterpret_cast<const float4*>(demod + (size_t)b * CO + obase_o);
#pragma unroll
    for (int j = 0; j < 4; ++j) {
      int o = obase_o + j;
      float dm = (j == 0) ? dmv.x : (j == 1) ? dmv.y : (j == 2) ? dmv.z : dmv.w;
      float* orow = out + (((size_t)b * CO + o) * HH + h0) * WW;
#pragma unroll
      for (int n = 0; n < 8; ++n) {
        int row = wpx * 2 + (n >> 2);
        int col = (n & 3) * 16 + llo;
        orow[(size_t)row * WW + col] = acc[m][n][j] * dm;
      }
    }
  }
}

extern "C" void kernel_launch(void* const* d_in, const int* in_sizes, int n_in,
                              void* d_out, int out_size, void* d_ws, size_t ws_size,
                              hipStream_t stream) {
  const float* X      = (const float*)d_in[0];
  const float* cond_v = (const float*)d_in[1];
  const float* conv_w = (const float*)d_in[2];
  const float* w0     = (const float*)d_in[3];
  const float* b0     = (const float*)d_in[4];
  const float* w1     = (const float*)d_in[5];
  const float* b1     = (const float*)d_in[6];
  const float* w_out  = (const float*)d_in[7];
  const float* b_out  = (const float*)d_in[8];
  float* out = (float*)d_out;

  char* ws = (char*)d_ws;
  const size_t XS_BYTES  = (size_t)NB * HP * WP * CI * 2;
  const size_t WT_BYTES  = (size_t)9 * 65536 * 2;                // Wt2: 9 x 65536 bf16
  const size_t WSQ_BYTES = (size_t)CO * CI * 4;
  __hip_bfloat16* Xs  = (__hip_bfloat16*)ws;
  __hip_bfloat16* Wt2 = (__hip_bfloat16*)(ws + XS_BYTES);
  float* wsq   = (float*)(ws + XS_BYTES + WT_BYTES);
  float* h0b   = (float*)(ws + XS_BYTES + WT_BYTES + WSQ_BYTES);
  float* h1b   = h0b + NB * CC;
  float* scale = h1b + NB * CC;
  float* demod = scale + NB * CI;

  k_repack<<<(CO * CI) / 256, 256, 0, stream>>>(conv_w, Wt2, wsq);
  k_mlp<CC, CC, true, false, 128><<<NB * (CC / 128), 128, 0, stream>>>(cond_v, w0, b0, h0b);
  k_mlp<CC, CC, true, false, 128><<<NB * (CC / 128), 128, 0, stream>>>(h0b, w1, b1, h1b);
  k_mlp<CC, CI, false, true, 128><<<NB * (CI / 128), 128, 0, stream>>>(h1b, w_out, b_out, scale);
  k_demod<<<NB, CO, 0, stream>>>(wsq, scale, demod);
  k_scalex<<<NB * 64 * 4, 256, 0, stream>>>(X, scale, Xs);
  // main conv: 512 blocks of 256 threads -> 2 blocks/CU
  k_conv<<<NB * 32, 256, 0, stream>>>(Xs, Wt2, demod, out);
}

// Round 15
// 130.039 us; speedup vs baseline: 1.1114x; 1.1114x over previous
//
#include <hip/hip_runtime.h>
#include <hip/hip_bf16.h>
#include <cstdint>

#define NB 16
#define CI 256
#define CO 256
#define HH 64
#define WW 64
#define CC 512
#define HP 66
#define WP 66

typedef short short8 __attribute__((ext_vector_type(8)));
typedef float floatx4 __attribute__((ext_vector_type(4)));
typedef unsigned int uintx4 __attribute__((ext_vector_type(4)));

__device__ __forceinline__ void g2lds16(const void* g, void* l) {
  __builtin_amdgcn_global_load_lds((const __attribute__((address_space(1))) void*)g,
                                   (__attribute__((address_space(3))) void*)l, 16, 0, 0);
}

#define ASM_VMCNT0() do { __builtin_amdgcn_sched_barrier(0);               \
                          asm volatile("s_waitcnt vmcnt(0)" ::: "memory"); \
                          __builtin_amdgcn_sched_barrier(0); } while (0)
#define RAW_BAR() do { __builtin_amdgcn_sched_barrier(0);  \
                       __builtin_amdgcn_s_barrier();       \
                       __builtin_amdgcn_sched_barrier(0); } while (0)

// ---------------- fused: weight repack (blocks 0..255) + MLP layer 0 (blocks 256..287) ----------------
// Independent work at the same dependency level -> one launch.
// Repack: fp32 [O][I][3][3] -> bf16 Wt2[t][kc][ks][o][8] (k-major, conv af loads coalesced):
//   (t,o,i) -> Wt2[t*65536 + ((i>>5)*4 + ((i>>3)&3))*2048 + o*8 + (i&7)]; wsq[o][i] = sum_t w^2.
// MLP0: h0b[b][j] = silu(w0[j] . cond_v[b] + b0[j]), 512 outputs x 16 b, BJ=256.
__global__ __launch_bounds__(256)
void k_pre(const float* __restrict__ cw, __hip_bfloat16* __restrict__ Wt2,
           float* __restrict__ wsq,
           const float* __restrict__ cond_v, const float* __restrict__ w0,
           const float* __restrict__ b0, float* __restrict__ h0b) {
  int bid = blockIdx.x;
  if (bid < 256) {
    int gid = bid * 256 + threadIdx.x;    // gid = o*CI + i
    int o = gid >> 8;
    int i = gid & 255;
    int base_i = ((i >> 5) * 4 + ((i >> 3) & 3)) * 2048 + o * 8 + (i & 7);
    const float* p = cw + (size_t)gid * 9;
    float s = 0.0f;
#pragma unroll
    for (int t = 0; t < 9; ++t) {
      float v = p[t];
      s += v * v;
      Wt2[(size_t)t * 65536 + base_i] = __float2bfloat16(v);
    }
    wsq[gid] = s;
  } else {
    __shared__ float4 sin4[CC / 4];
    int r = bid - 256;                    // 0..31
    int b = r >> 1;
    int j = (r & 1) * 256 + threadIdx.x;
    const float4* in4 = reinterpret_cast<const float4*>(cond_v + (size_t)b * CC);
    if (threadIdx.x < CC / 4) sin4[threadIdx.x] = in4[threadIdx.x];
    __syncthreads();
    float a = b0[j];
    const float4* wr = reinterpret_cast<const float4*>(w0 + (size_t)j * CC);
#pragma unroll 8
    for (int kk = 0; kk < CC / 4; ++kk) {
      float4 w_ = wr[kk], v_ = sin4[kk];
      a += w_.x * v_.x + w_.y * v_.y + w_.z * v_.z + w_.w * v_.w;
    }
    a = a / (1.0f + __expf(-a));
    h0b[(size_t)b * CC + j] = a;
  }
}

// ---------------- MLP layer (split version: latency-friendly grids) ----------------
template<int KD, int N, bool SILU, bool PLUSONE, int BJ>
__global__ void k_mlp(const float* __restrict__ in, const float* __restrict__ w,
                      const float* __restrict__ bias, float* __restrict__ out) {
  __shared__ float4 sin4[KD / 4];
  const int nb = N / BJ;
  int b = blockIdx.x / nb;
  int j = (blockIdx.x % nb) * BJ + threadIdx.x;
  const float4* in4 = reinterpret_cast<const float4*>(in + (size_t)b * KD);
  for (int k = threadIdx.x; k < KD / 4; k += BJ) sin4[k] = in4[k];
  __syncthreads();
  float acc = bias[j];
  const float4* wr = reinterpret_cast<const float4*>(w + (size_t)j * KD);
#pragma unroll 8
  for (int kk = 0; kk < KD / 4; ++kk) {
    float4 wv = wr[kk];
    float4 sv = sin4[kk];
    acc += wv.x * sv.x + wv.y * sv.y + wv.z * sv.z + wv.w * sv.w;
  }
  if (SILU) acc = acc / (1.0f + __expf(-acc));
  if (PLUSONE) acc += 1.0f;
  out[(size_t)b * N + j] = acc;
}

// ---------------- fused: X*scale -> padded NHWC bf16 (blocks 0..4095) + demod (4096..4111) ----------------
__global__ void k_scalex_demod(const float* __restrict__ X, const float* __restrict__ scale,
                               __hip_bfloat16* __restrict__ Xs,
                               const float* __restrict__ wsq, float* __restrict__ demod) {
  int bid = blockIdx.x;
  int t = threadIdx.x;
  if (bid >= NB * 256) {
    // ---- demod: b = bid - 4096, o = tid ----
    __shared__ float s2[CI];
    int b = bid - NB * 256;
    int o = t;
    float sv = scale[b * CI + o];
    s2[o] = sv * sv;
    __syncthreads();
    float acc = 0.0f;
    const float4* wr = reinterpret_cast<const float4*>(wsq + (size_t)o * CI);
    const float4* s4 = reinterpret_cast<const float4*>(s2);
#pragma unroll 8
    for (int i = 0; i < CI / 4; ++i) {
      float4 wv = wr[i], sq = s4[i];
      acc += wv.x * sq.x + wv.y * sq.y + wv.z * sq.z + wv.w * sq.w;
    }
    demod[(size_t)b * CO + o] = rsqrtf(acc + 1e-8f);
    return;
  }
  __shared__ float tile[64][68];
  __shared__ float ssc[64];
  int b = bid >> 8;
  int rem = bid & 255;
  int h = rem >> 2;
  int i0 = (rem & 3) * 64;
  if (t < 64) ssc[t] = scale[b * CI + i0 + t];

  __hip_bfloat16* xs_img = Xs + (size_t)b * HP * WP * CI;
  uintx4 z = {0u, 0u, 0u, 0u};
  if (t < 16) {
    int px = (t >> 3) * 65;
    int sl = t & 7;
    *reinterpret_cast<uintx4*>(xs_img + (((size_t)(h + 1)) * WP + px) * CI + i0 + sl * 8) = z;
  }
  if (h == 0) {
    for (int u = t; u < 66 * 8; u += 256) {
      int px = u >> 3, sl = u & 7;
      *reinterpret_cast<uintx4*>(xs_img + ((size_t)px) * CI + i0 + sl * 8) = z;
    }
  }
  if (h == 63) {
    for (int u = t; u < 66 * 8; u += 256) {
      int px = u >> 3, sl = u & 7;
      *reinterpret_cast<uintx4*>(xs_img + ((size_t)65 * WP + px) * CI + i0 + sl * 8) = z;
    }
  }

  const float* src = X + (((size_t)b * CI + i0) * HH + h) * WW;
  int ii_base = t >> 4;                 // 0..15
  int w4 = (t & 15) * 4;
#pragma unroll
  for (int r2 = 0; r2 < 4; ++r2) {
    int ii = r2 * 16 + ii_base;
    int key = ((ii >> 3) & 7) << 2;
    *reinterpret_cast<float4*>(&tile[ii][w4 ^ key]) =
        *reinterpret_cast<const float4*>(src + (size_t)ii * HH * WW + w4);
  }
  __syncthreads();
  int u = t & 7;
  int wl = t >> 3;
  int key = u << 2;
#pragma unroll
  for (int iter = 0; iter < 2; ++iter) {
    int w2 = wl + iter * 32;
    union { unsigned short us[8]; uintx4 v; } pk;
#pragma unroll
    for (int j = 0; j < 8; ++j) {
      int ii = u * 8 + j;
      float v = tile[ii][w2 ^ key] * ssc[ii];
      __hip_bfloat16 hb = __float2bfloat16(v);
      pk.us[j] = *reinterpret_cast<unsigned short*>(&hb);
    }
    *reinterpret_cast<uintx4*>(xs_img + (((size_t)(h + 1)) * WP + (w2 + 1)) * CI + i0 + u * 8) = pk.v;
  }
}

// ---------------- main conv: barrier-free within chunk; af from global; bq JIT per n ----------------
// Round-14 structure with the spill fixed: bq is read and consumed per n (round-12's proven
// register pattern: live bq = 1, not 8), and a sched_barrier(0) at tap end stops the compiler
// from hoisting af loads across taps (bounded live ranges). af: 4 coalesced dwordx4 from the
// k-major Wt2 (L2-resident). No A-LDS -> no per-tap barrier; waves drift within a chunk so
// one wave's LDS reads / af latency overlap other waves' MFMAs. Barriers only at the 8 chunk
// boundaries. LDS: X dbuf 2 x 28672 -> 2 blocks/CU. Arch regs ~90 < 128 cap (no spill).
__global__ __launch_bounds__(256, 2)
void k_conv(const __hip_bfloat16* __restrict__ Xs, const __hip_bfloat16* __restrict__ Wt2,
            const float* __restrict__ demod, float* __restrict__ out) {
  __shared__ __align__(16) char lds[2 * 28672];
  char* sX0 = lds;

  // bijective XCD swizzle: 512 blocks -> 64 consecutive wg per XCD = 2 images per XCD L2
  int wg = (blockIdx.x & 7) * 64 + (blockIdx.x >> 3);
  int b = wg >> 5;
  int rem = wg & 31;
  int ht = rem >> 1;                    // 0..15
  int ob = rem & 1;
  int h0 = ht * 4;                      // 4 output rows
  int o0 = ob * 128;

  int tid = threadIdx.x;
  int wv = tid >> 6;                    // 0..3
  int lane = tid & 63;
  int lhi = lane >> 4;                  // 0..3
  int llo = lane & 15;                  // 0..15
  int wo2 = wv >> 1;                    // 0..1  o-group
  int wpx = wv & 1;                     // 0..1  px-group (2 rows)

  floatx4 acc[4][8];
#pragma unroll
  for (int m = 0; m < 4; ++m)
#pragma unroll
    for (int n = 0; n < 8; ++n) acc[m][n] = (floatx4){0.f, 0.f, 0.f, 0.f};

  const __hip_bfloat16* xs_img = Xs + (size_t)b * HP * WP * CI;

  // X staging slots: 28 1-KB blocks, 7 per wave; source carries the read-side k-slot XOR.
  int xoff[7];
#pragma unroll
  for (int s = 0; s < 7; ++s) {
    int j = wv + 4 * s;
    int pr = 16 * j + (lane >> 2);      // LDS pixel-row 0..447
    int prc = pr > 431 ? 431 : pr;      // pad block: clamp source (never read)
    int lr = prc / 72;
    int wp = prc - lr * 72;
    if (wp > 65) wp = 65;               // pitch pad: clamp source (never read)
    int ksl = (lane & 3) ^ ((pr >> 1) & 3);
    xoff[s] = ((h0 + lr) * WP + wp) * CI + ksl * 8;
  }
  // af global element-offsets within a (t,kc) segment of Wt2: lhi*2048 + o*8
  int aofs[4];
#pragma unroll
  for (int m = 0; m < 4; ++m)
    aofs[m] = lhi * 2048 + (o0 + wo2 * 64 + m * 16 + llo) * 8;

  // ---- prologue: stage X(0) fully; drain; barrier ----
#pragma unroll
  for (int s = 0; s < 7; ++s)
    g2lds16(xs_img + xoff[s], sX0 + (wv + 4 * s) * 1024);
  ASM_VMCNT0();
  RAW_BAR();

  for (int c = 0; c < 8; ++c) {
    const char* xbuf = sX0 + (c & 1) * 28672;
#pragma unroll
    for (int t = 0; t < 9; ++t) {
      // ---- af: 4 coalesced global loads from the k-major Wt2 (segment t*8+c) ----
      const __hip_bfloat16* wb = Wt2 + (size_t)(t * 8 + c) * 8192;
      short8 af[4];
#pragma unroll
      for (int m = 0; m < 4; ++m)
        af[m] = *reinterpret_cast<const short8*>(wb + aofs[m]);
      // ---- X(c+1) staging: 1 g2lds per wave at taps 0..6 ----
      if (t <= 6 && c < 7)
        g2lds16(xs_img + xoff[t] + (c + 1) * 32,
                sX0 + ((c + 1) & 1) * 28672 + (wv + 4 * t) * 1024);
      int kh = t / 3;
      int kw = t - kh * 3;
      __builtin_amdgcn_s_setprio(1);
      // ---- per-n: JIT bq read, consumed immediately (live bq = 1; no spill) ----
#pragma unroll
      for (int n = 0; n < 8; ++n) {
        int stripe = wpx * 2 + (n >> 2) + kh;            // 0..5
        int px = (n & 3) * 16 + llo + kw;                // 0..65
        int prl = stripe * 72 + px;
        short8 bq = *reinterpret_cast<const short8*>(
            xbuf + prl * 64 + ((lhi ^ ((prl >> 1) & 3)) << 4));
#pragma unroll
        for (int m = 0; m < 4; ++m)
          acc[m][n] = __builtin_amdgcn_mfma_f32_16x16x32_bf16(af[m], bq, acc[m][n], 0, 0, 0);
      }
      __builtin_amdgcn_s_setprio(0);
      __builtin_amdgcn_sched_barrier(0);  // stop cross-tap af hoisting (bounded live ranges)
    }
    // ---- chunk boundary: drain own g2lds, then block-wide rendezvous ----
    ASM_VMCNT0();
    if (c < 7) RAW_BAR();
  }

  // ---- epilogue: demod multiply, fp32 NCHW stores ----
#pragma unroll
  for (int m = 0; m < 4; ++m) {
    int obase_o = o0 + wo2 * 64 + m * 16 + lhi * 4;
    float4 dmv = *reinterpret_cast<const float4*>(demod + (size_t)b * CO + obase_o);
#pragma unroll
    for (int j = 0; j < 4; ++j) {
      int o = obase_o + j;
      float dm = (j == 0) ? dmv.x : (j == 1) ? dmv.y : (j == 2) ? dmv.z : dmv.w;
      float* orow = out + (((size_t)b * CO + o) * HH + h0) * WW;
#pragma unroll
      for (int n = 0; n < 8; ++n) {
        int row = wpx * 2 + (n >> 2);
        int col = (n & 3) * 16 + llo;
        orow[(size_t)row * WW + col] = acc[m][n][j] * dm;
      }
    }
  }
}

extern "C" void kernel_launch(void* const* d_in, const int* in_sizes, int n_in,
                              void* d_out, int out_size, void* d_ws, size_t ws_size,
                              hipStream_t stream) {
  const float* X      = (const float*)d_in[0];
  const float* cond_v = (const float*)d_in[1];
  const float* conv_w = (const float*)d_in[2];
  const float* w0     = (const float*)d_in[3];
  const float* b0     = (const float*)d_in[4];
  const float* w1     = (const float*)d_in[5];
  const float* b1     = (const float*)d_in[6];
  const float* w_out  = (const float*)d_in[7];
  const float* b_out  = (const float*)d_in[8];
  float* out = (float*)d_out;

  char* ws = (char*)d_ws;
  const size_t XS_BYTES  = (size_t)NB * HP * WP * CI * 2;
  const size_t WT_BYTES  = (size_t)9 * 65536 * 2;                // Wt2: 9 x 65536 bf16
  const size_t WSQ_BYTES = (size_t)CO * CI * 4;
  __hip_bfloat16* Xs  = (__hip_bfloat16*)ws;
  __hip_bfloat16* Wt2 = (__hip_bfloat16*)(ws + XS_BYTES);
  float* wsq   = (float*)(ws + XS_BYTES + WT_BYTES);
  float* h0b   = (float*)(ws + XS_BYTES + WT_BYTES + WSQ_BYTES);
  float* h1b   = h0b + NB * CC;
  float* scale = h1b + NB * CC;
  float* demod = scale + NB * CI;

  // fused: repack (256 blocks) + MLP layer 0 (32 blocks)
  k_pre<<<288, 256, 0, stream>>>(conv_w, Wt2, wsq, cond_v, w0, b0, h0b);
  k_mlp<CC, CC, true, false, 128><<<NB * (CC / 128), 128, 0, stream>>>(h0b, w1, b1, h1b);
  k_mlp<CC, CI, false, true, 128><<<NB * (CI / 128), 128, 0, stream>>>(h1b, w_out, b_out, scale);
  // fused: scalex (4096 blocks) + demod (16 blocks)
  k_scalex_demod<<<NB * 256 + NB, 256, 0, stream>>>(X, scale, Xs, wsq, demod);
  // main conv: 512 blocks of 256 threads -> 2 blocks/CU
  k_conv<<<NB * 32, 256, 0, stream>>>(Xs, Wt2, demod, out);
}